// Round 5
// baseline (38.839 us; speedup 1.0000x reference)
//
#include <hip/hip_runtime.h>

#define HID 16
#define XS_STRIDE 20   // floats per LDS row (80B): start banks of b128 reads cycle all 32

typedef float vfloat4 __attribute__((ext_vector_type(4)));

__global__ __launch_bounds__(256) void mpainn_coal_kernel(
    const float* __restrict__ x,
    const int* __restrict__ batch,
    const float* __restrict__ w1,
    const float* __restrict__ b1,
    const float* __restrict__ w2,
    const float* __restrict__ b2,
    float* __restrict__ out,   // [E (G floats) | F (3N floats)]
    int n, int G)
{
    __shared__ float w1s[HID * HID];
    __shared__ float b1s[HID];
    __shared__ float w2s[HID];
    __shared__ float b2s;
    __shared__ float xs[256 * XS_STRIDE];   // 20 KB

    const int tid = threadIdx.x;
    w1s[tid] = w1[tid];                      // block == 256 == HID*HID
    if (tid < HID) { b1s[tid] = b1[tid]; w2s[tid] = w2[tid]; }
    if (tid == 0) b2s = b2[0];

    const long long r0 = (long long)blockIdx.x * 256;   // first node of block

    // ---- cooperative, coalesced load of x[row, 48:64] into LDS ----
    // lane 4r+c loads 16B chunk c of row r: each wave instr = 16 rows x 64B contiguous
    {
        const int c  = tid & 3;
        const int rb = tid >> 2;             // 0..63
        #pragma unroll
        for (int g = 0; g < 4; ++g) {
            const int rl = rb + 64 * g;
            const long long row = r0 + rl;
            if (row < n) {
                const vfloat4 v = *(const vfloat4*)(x + row * 64 + 48 + 4 * c);
                *(vfloat4*)(xs + rl * XS_STRIDE + 4 * c) = v;
            }
        }
    }

    // ---- zero F_hat region for this block's nodes (grad wrt pos == 0) ----
    {
        float* __restrict__ F = out + G;
        const long long fstart = 3 * r0;                       // multiple of 4
        const long long fend   = 3 * (long long)n;
        const long long fblk_end = fstart + 768;
        if (fblk_end <= fend) {
            if (tid < 192) {
                const vfloat4 z = {0.f, 0.f, 0.f, 0.f};
                __builtin_nontemporal_store(z, (vfloat4*)(F + fstart + 4 * tid));
            }
        } else {
            for (long long idx = fstart + tid; idx < fend; idx += 256) F[idx] = 0.f;
        }
    }

    // ---- batch key ----
    const long long i = r0 + tid;
    int b = -1;
    if (i < n) b = batch[i];

    __syncthreads();

    // ---- per-node MLP from LDS ----
    float e = 0.f;
    if (i < n) {
        const float* xr = xs + tid * XS_STRIDE;
        const vfloat4 v0 = *(const vfloat4*)(xr + 0);
        const vfloat4 v1 = *(const vfloat4*)(xr + 4);
        const vfloat4 v2 = *(const vfloat4*)(xr + 8);
        const vfloat4 v3 = *(const vfloat4*)(xr + 12);
        float s[16] = { v0.x, v0.y, v0.z, v0.w,
                        v1.x, v1.y, v1.z, v1.w,
                        v2.x, v2.y, v2.z, v2.w,
                        v3.x, v3.y, v3.z, v3.w };
        float h[16];
        #pragma unroll
        for (int j = 0; j < 16; ++j) h[j] = b1s[j];
        #pragma unroll
        for (int k = 0; k < 16; ++k) {
            const float sk = s[k];
            #pragma unroll
            for (int j = 0; j < 16; ++j) h[j] += sk * w1s[k * 16 + j];
        }
        e = b2s;
        #pragma unroll
        for (int j = 0; j < 16; ++j) {
            const float a = h[j];
            const float sig = 1.0f / (1.0f + __expf(-a));
            e += (a * sig) * w2s[j];
        }
    }

    // ---- wave segmented scan over sorted batch + one atomic per run ----
    const int lane = tid & 63;
    #pragma unroll
    for (int d = 1; d < 64; d <<= 1) {
        const float oe = __shfl_up(e, (unsigned)d, 64);
        const int   ob = __shfl_up(b, (unsigned)d, 64);
        if (lane >= d && ob == b) e += oe;
    }
    const int nb = __shfl_down(b, 1, 64);
    const bool last_of_run = (lane == 63) || (nb != b);
    if (b >= 0 && last_of_run) atomicAdd(&out[b], e);
}

extern "C" void kernel_launch(void* const* d_in, const int* in_sizes, int n_in,
                              void* d_out, int out_size, void* d_ws, size_t ws_size,
                              hipStream_t stream)
{
    const float* x     = (const float*)d_in[0];
    // d_in[1] = pos (unused: energy() ignores p, so F_hat == 0)
    const int*   batch = (const int*)d_in[2];
    // d_in[3] = num_graphs scalar
    const float* w1    = (const float*)d_in[4];
    const float* b1    = (const float*)d_in[5];
    const float* w2    = (const float*)d_in[6];
    const float* b2    = (const float*)d_in[7];

    const int n = in_sizes[2];          // N = 1,000,000
    const int G = out_size - 3 * n;     // 8192
    float* out = (float*)d_out;

    // Zero only the E region (32 KB); F region is written by the kernel.
    (void)hipMemsetAsync(d_out, 0, (size_t)G * sizeof(float), stream);

    const int block = 256;
    const int grid = (n + block - 1) / block;
    mpainn_coal_kernel<<<grid, block, 0, stream>>>(x, batch, w1, b1, w2, b2, out, n, G);
}

// Round 6
// 36.529 us; speedup vs baseline: 1.0632x; 1.0632x over previous
//
#include <hip/hip_runtime.h>

#define HID 16

typedef float vfloat2 __attribute__((ext_vector_type(2)));

__global__ __launch_bounds__(256) void mpainn_energy2_kernel(
    const float* __restrict__ x,
    const int* __restrict__ batch,
    const float* __restrict__ w1,
    const float* __restrict__ b1,
    const float* __restrict__ w2,
    const float* __restrict__ b2,
    float* __restrict__ out,   // [E (G floats) | F (3N floats)]
    int n, int G)
{
    __shared__ float w1s[HID * HID];
    __shared__ float b1s[HID];
    __shared__ float w2s[HID];
    __shared__ float b2s;

    const int tid = threadIdx.x;
    if (tid < HID * HID) w1s[tid] = w1[tid];
    if (tid < HID) { b1s[tid] = b1[tid]; w2s[tid] = w2[tid]; }
    if (tid == 0) b2s = b2[0];
    __syncthreads();

    const long long gid = (long long)blockIdx.x * blockDim.x + tid;
    const long long i0 = 2 * gid;
    const long long i1 = i0 + 1;
    const int lane = tid & 63;

    // ---- zero the F_hat region (grad wrt pos is exactly 0) ----
    float* __restrict__ F = out + G;
    if (i1 < n) {
        const vfloat2 z = {0.f, 0.f};
        vfloat2* fp = (vfloat2*)(F + 6 * gid);
        __builtin_nontemporal_store(z, fp);
        __builtin_nontemporal_store(z, fp + 1);
        __builtin_nontemporal_store(z, fp + 2);
    } else if (i0 < n) {
        F[3 * i0] = 0.f; F[3 * i0 + 1] = 0.f; F[3 * i0 + 2] = 0.f;
    }

    // ---- per-node tiny MLP ----
    float e0 = 0.f, e1 = 0.f;
    int b0 = -1, b1k = -1;

    if (i0 < n) b0  = batch[i0];
    if (i1 < n) b1k = batch[i1];

    auto energy = [&](long long i) -> float {
        const float4* p = (const float4*)(x + i * 64 + 48);
        float4 v0 = p[0], v1 = p[1], v2 = p[2], v3 = p[3];
        float s[16] = { v0.x, v0.y, v0.z, v0.w,
                        v1.x, v1.y, v1.z, v1.w,
                        v2.x, v2.y, v2.z, v2.w,
                        v3.x, v3.y, v3.z, v3.w };
        float h[16];
        #pragma unroll
        for (int j = 0; j < 16; ++j) h[j] = b1s[j];
        #pragma unroll
        for (int k = 0; k < 16; ++k) {
            const float sk = s[k];
            #pragma unroll
            for (int j = 0; j < 16; ++j) h[j] += sk * w1s[k * 16 + j];
        }
        float e = b2s;
        #pragma unroll
        for (int j = 0; j < 16; ++j) {
            const float a = h[j];
            const float sig = 1.0f / (1.0f + __expf(-a));
            e += (a * sig) * w2s[j];
        }
        return e;
    };

    if (i0 < n) e0 = energy(i0);
    if (i1 < n) e1 = energy(i1);

    // ---- segmented reduction over sorted batch, 2 nodes/thread ----
    // Per-thread compressed value: key = b1k, value = e1 (+ e0 if same key).
    float v = (b0 == b1k) ? (e0 + e1) : e1;
    const int k = b1k;

    // Wave-level segmented inclusive scan on (v, k).
    #pragma unroll
    for (int d = 1; d < 64; d <<= 1) {
        const float ov = __shfl_up(v, (unsigned)d, 64);
        const int   ok = __shfl_up(k, (unsigned)d, 64);
        if (lane >= d && ok == k) v += ov;
    }

    // Flush e0's run if it ends inside this thread (b0 != b1k).
    const float pv = __shfl_up(v, 1, 64);   // lane-1 inclusive value
    const int   pk = __shfl_up(k, 1, 64);   // lane-1 key
    if (b0 >= 0 && b0 != k) {
        float t = e0;
        if (lane > 0 && pk == b0) t += pv;
        atomicAdd(&out[b0], t);
    }

    // Flush the tail run (key k) if the next thread starts a different batch.
    const int nb0 = __shfl_down(b0, 1, 64);
    const bool last = (lane == 63) || (nb0 != k);
    if (k >= 0 && last) atomicAdd(&out[k], v);
}

extern "C" void kernel_launch(void* const* d_in, const int* in_sizes, int n_in,
                              void* d_out, int out_size, void* d_ws, size_t ws_size,
                              hipStream_t stream)
{
    const float* x     = (const float*)d_in[0];
    // d_in[1] = pos (unused: energy() ignores p, so F_hat == 0)
    const int*   batch = (const int*)d_in[2];
    // d_in[3] = num_graphs scalar (== 8192)
    const float* w1    = (const float*)d_in[4];
    const float* b1    = (const float*)d_in[5];
    const float* w2    = (const float*)d_in[6];
    const float* b2    = (const float*)d_in[7];

    const int n = in_sizes[2];          // N = 1,000,000
    const int G = out_size - 3 * n;     // 8192
    float* out = (float*)d_out;

    // Zero only the E region (32 KB); F region is written by the kernel.
    (void)hipMemsetAsync(d_out, 0, (size_t)G * sizeof(float), stream);

    const long long pairs = ((long long)n + 1) / 2;
    const int block = 256;
    const int grid = (int)((pairs + block - 1) / block);
    mpainn_energy2_kernel<<<grid, block, 0, stream>>>(x, batch, w1, b1, w2, b2, out, n, G);
}